// Round 11
// baseline (217.024 us; speedup 1.0000x reference)
//
#include <hip/hip_runtime.h>

#define N_TOK 2048
#define B_SZ  8
#define E_DIM 256
#define H_DIM 512
#define ITERS (N_TOK / 32)     // 64
#define QROWS 64               // q-rows per block

typedef __attribute__((ext_vector_type(8))) short bf16x8;
typedef __attribute__((ext_vector_type(4))) float f32x4;
typedef __attribute__((ext_vector_type(4))) unsigned short u16x4;

__device__ __forceinline__ unsigned short f2bf(float f) {
    union { float f; unsigned u; } v; v.f = f;
    unsigned r = v.u + 0x7FFF + ((v.u >> 16) & 1);   // RNE
    return (unsigned short)(r >> 16);
}
__device__ __forceinline__ float bf2f(unsigned short b) {
    union { unsigned u; float f; } v; v.u = ((unsigned)b) << 16;
    return v.f;
}

// ---- Kernel 1: fused prep (vectorized, verified R7) ------------------------
__global__ void prep_kernel(const float* __restrict__ x,
                            const float* __restrict__ hptr,
                            unsigned short* __restrict__ Xn,
                            unsigned short* __restrict__ Vp,
                            float* __restrict__ sumsq) {
    int bid = blockIdx.x;
    int t = threadIdx.x;
    if (bid == 0 && t == 0) *sumsq = 0.0f;
    if (bid < (N_TOK * B_SZ) / 4) {
        // ---- norm path: 4 rows/block, one per wave ----
        int w = t >> 6, lane = t & 63;
        int r = bid * 4 + w;                 // row in x memory order: r = n*B + b
        int n = r >> 3, b = r & 7;
        float4 v = *(const float4*)(x + (size_t)r * E_DIM + lane * 4);
        float s = v.x * v.x + v.y * v.y + v.z * v.z + v.w * v.w;
        #pragma unroll
        for (int o = 32; o > 0; o >>= 1) s += __shfl_xor(s, o);
        float rn = 1.0f / sqrtf(s);
        u16x4 pk;
        pk[0] = f2bf(v.x * rn); pk[1] = f2bf(v.y * rn);
        pk[2] = f2bf(v.z * rn); pk[3] = f2bf(v.w * rn);
        int u = lane >> 1, half = lane & 1;
        *(u16x4*)(Xn + ((size_t)b * N_TOK + n) * E_DIM
                     + (size_t)((u ^ (n & 7)) * 8 + half * 4)) = pk;
    } else {
        // ---- pack-V path (float4 loads) ----
        int lin = bid - (N_TOK * B_SZ) / 4;    // 8192 blocks: (64, 16, 8)
        int jb = lin & 63, hb = (lin >> 6) & 15, b = lin >> 10;
        __shared__ __attribute__((aligned(16))) float tile[32][36];
        int j0 = jb * 32, h0 = hb * 32;
        {
            int j = t >> 3, c = (t & 7) * 4;
            float4 v = *(const float4*)(hptr +
                ((size_t)(j0 + j) * B_SZ + b) * H_DIM + h0 + c);
            *(float4*)(&tile[j][c]) = v;
        }
        __syncthreads();
        size_t base = ((size_t)b * (N_TOK / 32) + jb) * (H_DIM * 32);
        int hcl = t >> 3, jg = (t >> 1) & 3, half = t & 1;
        int hc = h0 + hcl;
        u16x4 pk;
        #pragma unroll
        for (int k = 0; k < 4; k++)
            pk[k] = f2bf(tile[jg * 8 + half * 4 + k][hcl]);
        *(u16x4*)(Vp + base + (size_t)(hc * 4 + (jg ^ ((hcl >> 1) & 3))) * 8
                     + half * 4) = pk;
    }
}

// ---- Kernel 2: flash attention, R9 body + T4 counted-vmcnt pipeline --------
// RESUBMIT of round 10 (container infra failure, no measurement). Audited:
// vmcnt accounting {stage(it):4 | V(it):4 | stage(it+1):4} -> vmcnt(8)
// retires exactly stage(it); "memory" clobbers pin vmem issue order; buffer
// reuse protected by two barriers; no divergent barrier -> no hang path.
// Theory: the invariant ~121us wall across R0/R2/R7/R9 is the top-of-loop
// __syncthreads = s_waitcnt vmcnt(0) full-drain per iter (m218 anti-pattern;
// counted vmcnt = +38-73%). Triple-buffer K, stage DEPTH=2 ahead, V register-
// prefetch 1 ahead (vfA/vfB macro-alternated, rule-#20-safe). Both barriers
// raw. Body math identical to R9 (V-dedup 64x256, fixed-shift softmax).
#define PT_STRIDE 40   // shorts

__launch_bounds__(256, 2)
__global__ void flash_kernel(const unsigned short* __restrict__ Xn,
                             const unsigned short* __restrict__ Vp,
                             float* __restrict__ out,
                             float* __restrict__ sumsq) {
    __shared__ __attribute__((aligned(16))) unsigned short Kbuf[3][32 * 256];
    __shared__ __attribute__((aligned(16))) unsigned short Pt[4][16 * PT_STRIDE];
    __shared__ float Lred[4][16];

    int b  = blockIdx.x;           // batch: linear-id % 8 == b -> XCD-pinned
    int q0 = blockIdx.y * QROWS;
    int z  = blockIdx.z;           // h-half
    int t = threadIdx.x;
    int w = t >> 6, lane = t & 63;
    int quad = lane >> 4, nm = lane & 15;
    // w = QK row-group AND PV col-slice (64 cols)

    const unsigned short* Kbase = Xn + (size_t)b * N_TOK * E_DIM;
    const unsigned short* Qrow =
        Xn + ((size_t)b * N_TOK + q0 + w * 16 + nm) * E_DIM;
    const unsigned short* Vtile0 = Vp + (size_t)b * (N_TOK / 32) * (H_DIM * 32);
    int col0 = z * 256 + w * 64;   // this wave's PV column base

    // Q fragments (swizzled layout: unit (ec*4+quad) ^ (row&7))
    bf16x8 qf[8];
    #pragma unroll
    for (int ec = 0; ec < 8; ec++)
        qf[ec] = *(const bf16x8*)(Qrow + (size_t)(((ec * 4 + quad) ^ (nm & 7)) * 8));

    f32x4 O[4][4];                 // [row-group][col-tile]
    #pragma unroll
    for (int i = 0; i < 4; i++)
        #pragma unroll
        for (int j = 0; j < 4; j++) O[i][j] = (f32x4){0.f, 0.f, 0.f, 0.f};
    float l_lane[4];
    #pragma unroll
    for (int r = 0; r < 4; r++) l_lane[r] = 0.0f;

    // K staging: 4 waves cooperatively copy a 16KB tile (swizzle pre-baked)
    auto stage = [&](int tile, int buf) {
        const unsigned short* src0 = Kbase + (size_t)tile * 32 * E_DIM;
        #pragma unroll
        for (int k = 0; k < 4; k++) {
            int chunk = w * 4 + k;                 // 0..15, 1KB each
            __builtin_amdgcn_global_load_lds(
                (const __attribute__((address_space(1))) unsigned int*)
                    (src0 + (size_t)chunk * 512 + lane * 8),
                (__attribute__((address_space(3))) unsigned int*)
                    (&Kbuf[buf][chunk * 512]),
                16, 0, 0);
        }
    };

    int vswz = (quad ^ ((nm >> 1) & 3)) * 8;

    // Prologue issue order: stage(0), V(0), stage(1)
    // -> iter-0 queue: {S0 oldest | V0 | S1}; vmcnt(8) retires S0.
    bf16x8 vfA[4], vfB[4];
    stage(0, 0);
    {
        const unsigned short* Vt = Vtile0;
        #pragma unroll
        for (int tt = 0; tt < 4; tt++) {
            int hc = col0 + tt * 16 + nm;
            vfA[tt] = *(const bf16x8*)(Vt + (size_t)(hc * 4) * 8 + vswz);
        }
    }
    stage(1, 1);

#define FLASH_BODY(IT, VC, VN) do {                                            \
    /* counted wait: retire exactly stage(IT); keep V(IT)+stage(IT+1) */       \
    if ((IT) < ITERS - 1) asm volatile("s_waitcnt vmcnt(8)" ::: "memory");     \
    else                  asm volatile("s_waitcnt vmcnt(4)" ::: "memory");     \
    __builtin_amdgcn_s_barrier();                                              \
    asm volatile("" ::: "memory");                                             \
    const unsigned short* KB = &Kbuf[(IT) % 3][0];                             \
    /* QK^T: row-group w (16 rows) x all 32 keys, K=256, 2 ILP chains */       \
    f32x4 sa = (f32x4){0.f,0.f,0.f,0.f}, sb = (f32x4){0.f,0.f,0.f,0.f};        \
    _Pragma("unroll")                                                          \
    for (int ec = 0; ec < 8; ec++) {                                           \
        int u = ((ec * 4 + quad) ^ (nm & 7)) * 8;                              \
        bf16x8 kf0 = *(const bf16x8*)(KB + nm * 256 + u);                      \
        bf16x8 kf1 = *(const bf16x8*)(KB + (16 + nm) * 256 + u);               \
        sa = __builtin_amdgcn_mfma_f32_16x16x32_bf16(qf[ec], kf0, sa, 0,0,0);  \
        sb = __builtin_amdgcn_mfma_f32_16x16x32_bf16(qf[ec], kf1, sb, 0,0,0);  \
    }                                                                          \
    /* fixed-shift softmax: P = exp(s-1), publish both key halves */           \
    _Pragma("unroll")                                                          \
    for (int r = 0; r < 4; r++) {                                              \
        unsigned short pb0 = f2bf(__expf(sa[r] - 1.0f));                       \
        unsigned short pb1 = f2bf(__expf(sb[r] - 1.0f));                       \
        l_lane[r] += bf2f(pb0) + bf2f(pb1);                                    \
        Pt[w][(quad * 4 + r) * PT_STRIDE + nm]      = pb0;                     \
        Pt[w][(quad * 4 + r) * PT_STRIDE + 16 + nm] = pb1;                     \
    }                                                                          \
    asm volatile("s_waitcnt lgkmcnt(0)" ::: "memory");                         \
    __builtin_amdgcn_s_barrier();                                              \
    asm volatile("" ::: "memory");                                             \
    /* PV: all 4 row-groups x this wave's 4 col-tiles (vf reg-dep waited  */   \
    /* automatically by the compiler; leaves stage(IT+1) in flight) */         \
    _Pragma("unroll")                                                          \
    for (int rg = 0; rg < 4; rg++) {                                           \
        bf16x8 pf = *(const bf16x8*)(&Pt[rg][nm * PT_STRIDE + quad * 8]);      \
        _Pragma("unroll")                                                      \
        for (int ct = 0; ct < 4; ct++)                                         \
            O[rg][ct] = __builtin_amdgcn_mfma_f32_16x16x32_bf16(               \
                pf, VC[ct], O[rg][ct], 0, 0, 0);                               \
    }                                                                          \
    /* issue next-iter V then DEPTH-2 stage (order pins the queue) */          \
    if ((IT) + 1 < ITERS) {                                                    \
        const unsigned short* Vt = Vtile0 + (size_t)((IT)+1) * (H_DIM * 32);   \
        _Pragma("unroll")                                                      \
        for (int tt = 0; tt < 4; tt++) {                                       \
            int hc = col0 + tt * 16 + nm;                                      \
            VN[tt] = *(const bf16x8*)(Vt + (size_t)(hc * 4) * 8 + vswz);       \
        }                                                                      \
    }                                                                          \
    if ((IT) + 2 < ITERS) stage((IT) + 2, ((IT) + 2) % 3);                     \
} while (0)

    for (int itp = 0; itp < ITERS; itp += 2) {
        FLASH_BODY(itp,     vfA, vfB);
        FLASH_BODY(itp + 1, vfB, vfA);
    }
#undef FLASH_BODY

    // ---- epilogue: l for own row-group, share via LDS, normalize, write ----
    float lv[4];
    #pragma unroll
    for (int r = 0; r < 4; r++) {
        float v = l_lane[r];
        #pragma unroll
        for (int o = 1; o < 16; o <<= 1) v += __shfl_xor(v, o);
        lv[r] = v;
    }
    if (nm == 0) {
        #pragma unroll
        for (int r = 0; r < 4; r++) Lred[w][quad * 4 + r] = lv[r];
    }
    __syncthreads();

    float ss = 0.0f;
    #pragma unroll
    for (int rg = 0; rg < 4; rg++) {
        float linv[4];
        #pragma unroll
        for (int r = 0; r < 4; r++)
            linv[r] = 1.0f / Lred[rg][quad * 4 + r];
        #pragma unroll
        for (int ct = 0; ct < 4; ct++) {
            #pragma unroll
            for (int r = 0; r < 4; r++) {
                float val = O[rg][ct][r] * linv[r];
                int row = q0 + rg * 16 + quad * 4 + r;
                int col = col0 + ct * 16 + nm;
                out[((size_t)row * B_SZ + b) * H_DIM + col] = val;
                ss += val * val;
            }
        }
    }
    #pragma unroll
    for (int o = 1; o < 64; o <<= 1) ss += __shfl_xor(ss, o);
    if (lane == 0) atomicAdd(sumsq, ss);
}

// ---- Kernel 3: global-norm rescale ----------------------------------------
__global__ void scale_kernel(float* __restrict__ out,
                             const float* __restrict__ sumsq) {
    size_t idx = ((size_t)blockIdx.x * blockDim.x + threadIdx.x) * 4;
    float rs = 1.0f / sqrtf(*sumsq);
    float4 v = *(float4*)(out + idx);
    v.x *= rs; v.y *= rs; v.z *= rs; v.w *= rs;
    *(float4*)(out + idx) = v;
}

extern "C" void kernel_launch(void* const* d_in, const int* in_sizes, int n_in,
                              void* d_out, int out_size, void* d_ws, size_t ws_size,
                              hipStream_t stream) {
    const float* x = (const float*)d_in[0];
    const float* h = (const float*)d_in[1];
    float* out = (float*)d_out;

    unsigned short* Xn = (unsigned short*)d_ws;                  // 8.39 MB
    unsigned short* Vp = Xn + (size_t)B_SZ * N_TOK * E_DIM;      // 16.78 MB
    float* sumsq = (float*)(Vp + (size_t)B_SZ * N_TOK * H_DIM);  // 4 B

    prep_kernel<<<(N_TOK * B_SZ) / 4 + (N_TOK / 32) * (H_DIM / 32) * B_SZ,
                  256, 0, stream>>>(x, h, Xn, Vp, sumsq);
    flash_kernel<<<dim3(B_SZ, N_TOK / QROWS, 2), 256, 0, stream>>>(
        Xn, Vp, out, sumsq);
    scale_kernel<<<out_size / (4 * 256), 256, 0, stream>>>(out, sumsq);
}